// Round 4
// baseline (452.576 us; speedup 1.0000x reference)
//
#include <hip/hip_runtime.h>
#include <hip/hip_bf16.h>
#include <math.h>

#define NN 50000
#define NP 50048          // padded to 128-multiple for MFMA tiles
#define EE 800000
#define DIN 128
#define HID 256
#define NCLS 16
#define NPROT 512

typedef __attribute__((ext_vector_type(8))) short short8;
typedef __attribute__((ext_vector_type(4))) float f32x4;

__device__ inline unsigned short f2b(float f) {
    union { float f; unsigned u; } c; c.f = f;
    unsigned u = c.u;
    unsigned r = (u + 0x7FFFu + ((u >> 16) & 1u)) >> 16;
    return (unsigned short)r;
}
__device__ inline float b2f(unsigned short u) {
    union { unsigned u; float f; } c; c.u = ((unsigned)u) << 16; return c.f;
}

// async global->LDS, 16B per lane; LDS dest must be wave-uniform base + lane*16
#define GL2LDS16(g, l)                                                              \
    __builtin_amdgcn_global_load_lds(                                               \
        (const __attribute__((address_space(1))) unsigned int*)(g),                 \
        (__attribute__((address_space(3))) unsigned int*)(l), 16, 0, 0)

// ---------------- degree / CSR construction ----------------

__global__ __launch_bounds__(256) void k_count(const int* __restrict__ dst, int* __restrict__ cnt, int e) {
    int i = blockIdx.x * 256 + threadIdx.x;
    if (i < e) atomicAdd(&cnt[dst[i]], 1);
}

// block-local inclusive scan; also emits dis = rsqrt(deg+1)
__global__ __launch_bounds__(256) void k_scan1(const int* __restrict__ cnt, int* __restrict__ excl,
                                               int* __restrict__ bsum, float* __restrict__ dis, int n) {
    __shared__ int s[256];
    int t = threadIdx.x;
    int i = blockIdx.x * 256 + t;
    int v = (i < n) ? cnt[i] : 0;
    if (i < n) dis[i] = rsqrtf((float)v + 1.0f);
    s[t] = v; __syncthreads();
    for (int d = 1; d < 256; d <<= 1) {
        int add = (t >= d) ? s[t - d] : 0;
        __syncthreads();
        s[t] += add;
        __syncthreads();
    }
    if (i < n) excl[i] = s[t] - v;
    if (t == 255) bsum[blockIdx.x] = s[255];
}

__global__ __launch_bounds__(256) void k_scan2(const int* __restrict__ bsum, int* __restrict__ boff, int nb) {
    __shared__ int s[256];
    int t = threadIdx.x;
    int v = (t < nb) ? bsum[t] : 0;
    s[t] = v; __syncthreads();
    for (int d = 1; d < 256; d <<= 1) {
        int add = (t >= d) ? s[t - d] : 0;
        __syncthreads();
        s[t] += add;
        __syncthreads();
    }
    if (t < nb) boff[t] = s[t] - v;
}

__global__ __launch_bounds__(256) void k_scan3(const int* __restrict__ excl, const int* __restrict__ boff,
                                               int* __restrict__ off, int n, int e) {
    int i = blockIdx.x * 256 + threadIdx.x;
    if (i < n) off[i] = excl[i] + boff[blockIdx.x];
    if (i == 0) off[n] = e;
}

__global__ __launch_bounds__(256) void k_fill(const int* __restrict__ src, const int* __restrict__ dst,
                                              const int* __restrict__ off, int* __restrict__ cursor,
                                              const float* __restrict__ dis,
                                              int2* __restrict__ csr_e, int e) {
    int i = blockIdx.x * 256 + threadIdx.x;
    if (i >= e) return;
    int s = src[i], d = dst[i];
    int pos = atomicAdd(&cursor[d], 1);
    csr_e[off[d] + pos] = make_int2(s, __float_as_int(dis[s] * dis[d]));
}

// ---------------- fused prep: cast x -> bf16, transpose W0/W1 -> bf16 [n][k] ----------------

#define CAST_BLKS (NN * DIN / 4 / 256)   // 6250
#define WT0_BLKS  (DIN * HID / 256)      // 128
#define WT1_BLKS  (HID * HID / 256)      // 256

__global__ __launch_bounds__(256) void k_prep(const float* __restrict__ x, unsigned short* __restrict__ xb,
                                              const float* __restrict__ W0, unsigned short* __restrict__ Wt0,
                                              const float* __restrict__ W1, unsigned short* __restrict__ Wt1) {
    int b = blockIdx.x, t = threadIdx.x;
    if (b < CAST_BLKS) {
        int i = b * 256 + t;
        float4 v = ((const float4*)x)[i];
        ushort4 o; o.x = f2b(v.x); o.y = f2b(v.y); o.z = f2b(v.z); o.w = f2b(v.w);
        ((ushort4*)xb)[i] = o;
    } else if (b < CAST_BLKS + WT0_BLKS) {
        int i = (b - CAST_BLKS) * 256 + t;
        int k = i / HID, n = i - k * HID;
        Wt0[n * DIN + k] = f2b(W0[(size_t)k * HID + n]);
    } else {
        int i = (b - CAST_BLKS - WT0_BLKS) * 256 + t;
        int k = i / HID, n = i - k * HID;
        Wt1[n * HID + k] = f2b(W1[(size_t)k * HID + n]);
    }
}

// ---------------- bf16 MFMA GEMM: C[M,Nc] = A[Mp,K] @ Bt[Nc,K]^T ----------------
// mode 0: plain bf16 store (unguarded).  mode 2: +bias[col], relu, bf16 store (unguarded).

__global__ __launch_bounds__(256) void k_gemm_mfma(const unsigned short* __restrict__ A,
                                                   const unsigned short* __restrict__ Bt,
                                                   void* __restrict__ C, int M, int Nc, int K, int mode,
                                                   const float* __restrict__ bias) {
    __shared__ __align__(16) unsigned short As[128 * 32];  // 8 KB, unpadded (global_load_lds layout)
    __shared__ __align__(16) unsigned short Bs[128 * 32];
    const int t = threadIdx.x;
    const int lane = t & 63;
    const int quad = lane >> 4;
    const int l16 = lane & 15;
    const int wv = t >> 6;
    const int wm = (wv & 1) * 64, wn = (wv >> 1) * 64;
    const int m0 = blockIdx.y * 128, n0 = blockIdx.x * 128;

    f32x4 acc[4][4];
#pragma unroll
    for (int i = 0; i < 4; ++i)
#pragma unroll
        for (int j = 0; j < 4; ++j)
#pragma unroll
            for (int r = 0; r < 4; ++r) acc[i][j][r] = 0.0f;

    const int sr = t >> 2;         // staging row 0..63 (per half)
    const int sc = (t & 3) * 8;    // short offset in row: 0,8,16,24

    for (int k0 = 0; k0 < K; k0 += 32) {
        GL2LDS16(A + (size_t)(m0 + sr) * K + k0 + sc,       &As[t * 8]);
        GL2LDS16(A + (size_t)(m0 + 64 + sr) * K + k0 + sc,  &As[2048 + t * 8]);
        GL2LDS16(Bt + (size_t)(n0 + sr) * K + k0 + sc,      &Bs[t * 8]);
        GL2LDS16(Bt + (size_t)(n0 + 64 + sr) * K + k0 + sc, &Bs[2048 + t * 8]);
        __syncthreads();
        short8 af[4], bf[4];
#pragma unroll
        for (int i = 0; i < 4; ++i)
            af[i] = *(const short8*)&As[(wm + i * 16 + l16) * 32 + quad * 8];
#pragma unroll
        for (int j = 0; j < 4; ++j)
            bf[j] = *(const short8*)&Bs[(wn + j * 16 + l16) * 32 + quad * 8];
#pragma unroll
        for (int i = 0; i < 4; ++i)
#pragma unroll
            for (int j = 0; j < 4; ++j)
                acc[i][j] = __builtin_amdgcn_mfma_f32_16x16x32_bf16(af[i], bf[j], acc[i][j], 0, 0, 0);
        __syncthreads();
    }

#pragma unroll
    for (int i = 0; i < 4; ++i) {
        int rb = m0 + wm + i * 16 + quad * 4;
#pragma unroll
        for (int j = 0; j < 4; ++j) {
            int col = n0 + wn + j * 16 + l16;
#pragma unroll
            for (int rg = 0; rg < 4; ++rg) {
                int r = rb + rg;
                float v = acc[i][j][rg];
                if (mode == 0) {
                    ((unsigned short*)C)[(size_t)r * Nc + col] = f2b(v);
                } else {
                    v = fmaxf(v + bias[col], 0.0f);
                    ((unsigned short*)C)[(size_t)r * Nc + col] = f2b(v);
                }
            }
        }
    }
}

// ---------------- GCN aggregation (128-dim, raw): one wave per node ----------------
// Two-phase 8-wide gather pipeline: 8 row loads in flight before any FMA (latency-bound fix,
// round-3 counters: VGPR=20 showed the old macro serialized to ~1 outstanding load/wave).

__global__ __launch_bounds__(256) void k_agg128(const unsigned short* __restrict__ xw, const int* __restrict__ off,
                                                const int2* __restrict__ csr, const float* __restrict__ dis,
                                                unsigned short* __restrict__ out, int n) {
    int node = (blockIdx.x * 256 + threadIdx.x) >> 6;
    int lane = threadIdx.x & 63;
    if (node >= n) return;
    float d = dis[node];
    float w0 = d * d;
    ushort2 u = ((const ushort2*)(xw + (size_t)node * DIN))[lane];
    float a0 = w0 * b2f(u.x), a1 = w0 * b2f(u.y);
    int p = off[node], p1 = off[node + 1];
    while (p < p1) {
        int2 e0 = csr[(p + 0 < p1) ? p + 0 : p];
        int2 e1 = csr[(p + 1 < p1) ? p + 1 : p];
        int2 e2 = csr[(p + 2 < p1) ? p + 2 : p];
        int2 e3 = csr[(p + 3 < p1) ? p + 3 : p];
        int2 e4 = csr[(p + 4 < p1) ? p + 4 : p];
        int2 e5 = csr[(p + 5 < p1) ? p + 5 : p];
        int2 e6 = csr[(p + 6 < p1) ? p + 6 : p];
        int2 e7 = csr[(p + 7 < p1) ? p + 7 : p];
        ushort2 v0 = ((const ushort2*)(xw + (size_t)e0.x * DIN))[lane];
        ushort2 v1 = ((const ushort2*)(xw + (size_t)e1.x * DIN))[lane];
        ushort2 v2 = ((const ushort2*)(xw + (size_t)e2.x * DIN))[lane];
        ushort2 v3 = ((const ushort2*)(xw + (size_t)e3.x * DIN))[lane];
        ushort2 v4 = ((const ushort2*)(xw + (size_t)e4.x * DIN))[lane];
        ushort2 v5 = ((const ushort2*)(xw + (size_t)e5.x * DIN))[lane];
        ushort2 v6 = ((const ushort2*)(xw + (size_t)e6.x * DIN))[lane];
        ushort2 v7 = ((const ushort2*)(xw + (size_t)e7.x * DIN))[lane];
#define F128(q, eq, vq)                                                   \
        {                                                                 \
            float w = (p + q < p1) ? __int_as_float(eq.y) : 0.0f;         \
            a0 = fmaf(w, b2f(vq.x), a0); a1 = fmaf(w, b2f(vq.y), a1);     \
        }
        F128(0, e0, v0) F128(1, e1, v1) F128(2, e2, v2) F128(3, e3, v3)
        F128(4, e4, v4) F128(5, e5, v5) F128(6, e6, v6) F128(7, e7, v7)
#undef F128
        p += 8;
    }
    ushort2 o; o.x = f2b(a0); o.y = f2b(a1);
    ((ushort2*)(out + (size_t)node * DIN))[lane] = o;
}

// ---------------- GCN aggregation (256-dim): +bias then L2-normalize, emit bf16 + nx ----------------
// Same two-phase 8-wide gather pipeline.

__global__ __launch_bounds__(256) void k_agg256(const unsigned short* __restrict__ xw, const int* __restrict__ off,
                                                const int2* __restrict__ csr, const float* __restrict__ dis,
                                                const float* __restrict__ bias,
                                                unsigned short* __restrict__ out, float* __restrict__ nx, int n) {
    int node = (blockIdx.x * 256 + threadIdx.x) >> 6;
    int lane = threadIdx.x & 63;
    if (node >= n) return;
    float d = dis[node];
    float w0 = d * d;
    ushort4 u = ((const ushort4*)(xw + (size_t)node * HID))[lane];
    float a0 = w0 * b2f(u.x), a1 = w0 * b2f(u.y), a2 = w0 * b2f(u.z), a3 = w0 * b2f(u.w);
    int p = off[node], p1 = off[node + 1];
    while (p < p1) {
        int2 e0 = csr[(p + 0 < p1) ? p + 0 : p];
        int2 e1 = csr[(p + 1 < p1) ? p + 1 : p];
        int2 e2 = csr[(p + 2 < p1) ? p + 2 : p];
        int2 e3 = csr[(p + 3 < p1) ? p + 3 : p];
        int2 e4 = csr[(p + 4 < p1) ? p + 4 : p];
        int2 e5 = csr[(p + 5 < p1) ? p + 5 : p];
        int2 e6 = csr[(p + 6 < p1) ? p + 6 : p];
        int2 e7 = csr[(p + 7 < p1) ? p + 7 : p];
        ushort4 v0 = ((const ushort4*)(xw + (size_t)e0.x * HID))[lane];
        ushort4 v1 = ((const ushort4*)(xw + (size_t)e1.x * HID))[lane];
        ushort4 v2 = ((const ushort4*)(xw + (size_t)e2.x * HID))[lane];
        ushort4 v3 = ((const ushort4*)(xw + (size_t)e3.x * HID))[lane];
        ushort4 v4 = ((const ushort4*)(xw + (size_t)e4.x * HID))[lane];
        ushort4 v5 = ((const ushort4*)(xw + (size_t)e5.x * HID))[lane];
        ushort4 v6 = ((const ushort4*)(xw + (size_t)e6.x * HID))[lane];
        ushort4 v7 = ((const ushort4*)(xw + (size_t)e7.x * HID))[lane];
#define F256(q, eq, vq)                                                   \
        {                                                                 \
            float w = (p + q < p1) ? __int_as_float(eq.y) : 0.0f;         \
            a0 = fmaf(w, b2f(vq.x), a0); a1 = fmaf(w, b2f(vq.y), a1);     \
            a2 = fmaf(w, b2f(vq.z), a2); a3 = fmaf(w, b2f(vq.w), a3);     \
        }
        F256(0, e0, v0) F256(1, e1, v1) F256(2, e2, v2) F256(3, e3, v3)
        F256(4, e4, v4) F256(5, e5, v5) F256(6, e6, v6) F256(7, e7, v7)
#undef F256
        p += 8;
    }
    float4 b = ((const float4*)bias)[lane];
    a0 += b.x; a1 += b.y; a2 += b.z; a3 += b.w;
    // fused L2 row-normalize (reference: h /= ||h||, nx = ||h_normed|| recomputed)
    float ss = a0 * a0 + a1 * a1 + a2 * a2 + a3 * a3;
    for (int m = 32; m >= 1; m >>= 1) ss += __shfl_xor(ss, m, 64);
    float qn = sqrtf(ss);
    a0 /= qn; a1 /= qn; a2 /= qn; a3 /= qn;
    float s2 = a0 * a0 + a1 * a1 + a2 * a2 + a3 * a3;
    for (int m = 32; m >= 1; m >>= 1) s2 += __shfl_xor(s2, m, 64);
    if (lane == 0) nx[node] = sqrtf(s2);
    ushort4 o; o.x = f2b(a0); o.y = f2b(a1); o.z = f2b(a2); o.w = f2b(a3);
    ((ushort4*)(out + (size_t)node * HID))[lane] = o;
}

// ---------------- fused anchor gather + prototype head ----------------
// block = one anchor: stage h[prot[b]] row, emit aRb (bf16 for xrel GEMM) + na, then MLP + log_softmax.

__global__ __launch_bounds__(256) void k_gproto(const unsigned short* __restrict__ hb,
                                                const int* __restrict__ prot, const float* __restrict__ nx,
                                                unsigned short* __restrict__ aRb, float* __restrict__ na,
                                                const float* __restrict__ Wl1, const float* __restrict__ bl1,
                                                const float* __restrict__ Wl2, const float* __restrict__ bl2,
                                                float* __restrict__ outp) {
    __shared__ float sa[HID];
    __shared__ float st[HID];
    int row = blockIdx.x, t = threadIdx.x;
    int p = prot[row];
    unsigned short us = hb[(size_t)p * HID + t];
    aRb[(size_t)row * HID + t] = us;
    sa[t] = b2f(us);
    if (t == 0) na[row] = nx[p];
    __syncthreads();
    float acc = bl1[t];
#pragma unroll 8
    for (int k = 0; k < HID; ++k) acc = fmaf(sa[k], Wl1[k * HID + t], acc);
    st[t] = fmaxf(acc, 0.0f);
    __syncthreads();
    if (t < 64) {
        int c = t & 15, ch = t >> 4;
        float z = 0.f;
#pragma unroll 8
        for (int k = ch * 64; k < ch * 64 + 64; ++k) z = fmaf(st[k], Wl2[k * NCLS + c], z);
        z += __shfl_xor(z, 16, 64);
        z += __shfl_xor(z, 32, 64);
        z += bl2[c];
        float m = z;
        for (int d = 8; d >= 1; d >>= 1) m = fmaxf(m, __shfl_xor(m, d, 64));
        float e = expf(z - m);
        float s = e;
        for (int d = 8; d >= 1; d >>= 1) s += __shfl_xor(s, d, 64);
        if (t < 16) outp[row * NCLS + c] = z - m - logf(s);
    }
}

// ---------------- fused x_rel + partial final head ----------------
// Grid: 1564 blocks (4 n-chunks x 391 m-tiles), XCD-swizzled so the 4 chunks of one
// m-tile land on the SAME XCD (A-panel L2 reuse). Per block: 128 rows x 128 cols:
// K-loop MFMA -> rcp cosine-scale -> bf16 tile in XOR-swizzled LDS ->
//   (a) MFMA vs protoT slice -> fp32 partial out to opart[nc][NP][16]
//   (b) bf16->fp32 expand + dwordx4 fully-coalesced x_rel stores.
// LDS: 8 + 8 + 32 (Xs, XOR-swizzled) + 4.25 (pTc) = 52.25 KB -> 3 blocks/CU.

#define XSW(row, cs) (((cs) ^ (((row) & 7) << 3)))
#define NWGX (4 * (NP / 128))   // 1564

__global__ __launch_bounds__(256, 3) void k_xrel_out(const unsigned short* __restrict__ A,
                                                     const unsigned short* __restrict__ Bt,
                                                     const float* __restrict__ nx, const float* __restrict__ na,
                                                     const float* __restrict__ proto,
                                                     float* __restrict__ xrel, float* __restrict__ opart) {
    __shared__ __align__(16) unsigned short As[128 * 32];   // 8 KB
    __shared__ __align__(16) unsigned short Bs[128 * 32];   // 8 KB
    __shared__ __align__(16) unsigned short Xs[128 * 128];  // 32 KB bf16 x_rel tile (XOR-swizzled cols)
    __shared__ __align__(16) unsigned short pTc[16 * 136];  // 4.25 KB protoT slice

    // bijective XCD swizzle (m204): contiguous work ranges per XCD, work = m-major, chunk-minor
    const int bid = blockIdx.x;
    const int q = NWGX / 8, r = NWGX % 8;      // 195, 4
    const int xcd = bid & 7, li = bid >> 3;
    const int wk = (xcd < r ? xcd * (q + 1) : r * (q + 1) + (xcd - r) * q) + li;
    const int m0 = (wk >> 2) * 128;
    const int nc = wk & 3;
    const int n0 = nc * 128;

    const int t = threadIdx.x;
    const int lane = t & 63;
    const int quad = lane >> 4;
    const int l16 = lane & 15;
    const int wv = t >> 6;
    const int wm = (wv & 1) * 64, wn = (wv >> 1) * 64;

    // preload nx for this block's 16 row positions
    float nxv[4][4];
#pragma unroll
    for (int i = 0; i < 4; ++i)
#pragma unroll
        for (int rg = 0; rg < 4; ++rg) {
            int rr = m0 + wm + i * 16 + quad * 4 + rg;
            nxv[i][rg] = nx[rr < NN ? rr : NN - 1];
        }
    float nav[4];
#pragma unroll
    for (int j = 0; j < 4; ++j) nav[j] = na[n0 + wn + j * 16 + l16];

    const int sr = t >> 2;
    const int sc = (t & 3) * 8;

    f32x4 acc[4][4];
#pragma unroll
    for (int i = 0; i < 4; ++i)
#pragma unroll
        for (int j = 0; j < 4; ++j)
#pragma unroll
            for (int rr = 0; rr < 4; ++rr) acc[i][j][rr] = 0.0f;

    for (int k0 = 0; k0 < HID; k0 += 32) {
        GL2LDS16(A + (size_t)(m0 + sr) * HID + k0 + sc,       &As[t * 8]);
        GL2LDS16(A + (size_t)(m0 + 64 + sr) * HID + k0 + sc,  &As[2048 + t * 8]);
        GL2LDS16(Bt + (size_t)(n0 + sr) * HID + k0 + sc,      &Bs[t * 8]);
        GL2LDS16(Bt + (size_t)(n0 + 64 + sr) * HID + k0 + sc, &Bs[2048 + t * 8]);
        __syncthreads();
        short8 af[4], bf[4];
#pragma unroll
        for (int i = 0; i < 4; ++i)
            af[i] = *(const short8*)&As[(wm + i * 16 + l16) * 32 + quad * 8];
#pragma unroll
        for (int j = 0; j < 4; ++j)
            bf[j] = *(const short8*)&Bs[(wn + j * 16 + l16) * 32 + quad * 8];
#pragma unroll
        for (int i = 0; i < 4; ++i)
#pragma unroll
            for (int j = 0; j < 4; ++j)
                acc[i][j] = __builtin_amdgcn_mfma_f32_16x16x32_bf16(af[i], bf[j], acc[i][j], 0, 0, 0);
        __syncthreads();
    }

    // stage protoT slice for this chunk: pTc[c][kk] = bf16(proto[n0+kk][c])
    for (int i = t; i < 128 * NCLS; i += 256) {
        int kk = i >> 4, c = i & 15;
        pTc[c * 136 + kk] = f2b(proto[(n0 + kk) * NCLS + c]);
    }

    // cosine-scale (v_rcp) and stage bf16 tile into XOR-swizzled Xs
#pragma unroll
    for (int i = 0; i < 4; ++i) {
#pragma unroll
        for (int j = 0; j < 4; ++j) {
            int cl = wn + j * 16 + l16;
#pragma unroll
            for (int rg = 0; rg < 4; ++rg) {
                int row = wm + i * 16 + quad * 4 + rg;
                float s = fmaxf(nxv[i][rg] * nav[j], 1e-6f);
                float v = acc[i][j][rg] * __builtin_amdgcn_rcpf(s);
                Xs[row * 128 + XSW(row, cl)] = f2b(v);
            }
        }
    }
    __syncthreads();

    // (a) partial out: wave wv owns local rows wv*32 .. wv*32+31; k = this chunk's 128 cols
    f32x4 oacc[2];
#pragma unroll
    for (int rr = 0; rr < 4; ++rr) { oacc[0][rr] = 0.0f; oacc[1][rr] = 0.0f; }
#pragma unroll
    for (int ii = 0; ii < 2; ++ii) {
        int rb = wv * 32 + ii * 16;
#pragma unroll
        for (int ks = 0; ks < 4; ++ks) {
            int row = rb + l16;
            short8 af = *(const short8*)&Xs[row * 128 + XSW(row, ks * 32 + quad * 8)];
            short8 pb = *(const short8*)&pTc[l16 * 136 + ks * 32 + quad * 8];
            oacc[ii] = __builtin_amdgcn_mfma_f32_16x16x32_bf16(af, pb, oacc[ii], 0, 0, 0);
        }
    }
#pragma unroll
    for (int ii = 0; ii < 2; ++ii)
#pragma unroll
        for (int rg = 0; rg < 4; ++rg) {
            int lrow = wv * 32 + ii * 16 + quad * 4 + rg;
            opart[((size_t)nc * NP + m0 + lrow) * NCLS + l16] = oacc[ii][rg];
        }

    // (b) coalesced x_rel stores: bf16 -> fp32 expand, 16 lanes cover 512 B of one row
#pragma unroll
    for (int it = 0; it < 8; ++it) {
        int idx = it * 256 + t;          // 0..2047
        int row = idx >> 4;              // 0..127
        int c8 = (idx & 15) * 8;         // 0,8,..,120
        int rr = m0 + row;
        if (rr < NN) {
            short8 u = *(const short8*)&Xs[row * 128 + XSW(row, c8)];
            float* dst = &xrel[(size_t)rr * NPROT + n0 + c8];
            float4 v0, v1;
            v0.x = b2f((unsigned short)u[0]); v0.y = b2f((unsigned short)u[1]);
            v0.z = b2f((unsigned short)u[2]); v0.w = b2f((unsigned short)u[3]);
            v1.x = b2f((unsigned short)u[4]); v1.y = b2f((unsigned short)u[5]);
            v1.z = b2f((unsigned short)u[6]); v1.w = b2f((unsigned short)u[7]);
            *(float4*)dst = v0;
            *(float4*)(dst + 4) = v1;
        }
    }
}

// ---------------- final reduce: out = log_softmax(sum of 4 chunk partials) ----------------

__global__ __launch_bounds__(256) void k_reduce(const float* __restrict__ opart, float* __restrict__ out) {
    int i = blockIdx.x * 256 + threadIdx.x;   // over NP*16
    int row = i >> 4, c = i & 15;
    float z = opart[i] + opart[(size_t)NP * NCLS + i] + opart[(size_t)2 * NP * NCLS + i] +
              opart[(size_t)3 * NP * NCLS + i];
    float mx = z;
    for (int d = 8; d >= 1; d >>= 1) mx = fmaxf(mx, __shfl_xor(mx, d, 64));
    float e = expf(z - mx);
    float s = e;
    for (int d = 8; d >= 1; d >>= 1) s += __shfl_xor(s, d, 64);
    if (row < NN) out[(size_t)row * NCLS + c] = z - mx - logf(s);
}

// ---------------- launch ----------------

extern "C" void kernel_launch(void* const* d_in, const int* in_sizes, int n_in,
                              void* d_out, int out_size, void* d_ws, size_t ws_size,
                              hipStream_t stream) {
    const float* x    = (const float*)d_in[0];
    const int*   eidx = (const int*)d_in[1];
    const int*   prot = (const int*)d_in[2];
    const float* W0  = (const float*)d_in[4];
    const float* b0  = (const float*)d_in[5];
    const float* W1  = (const float*)d_in[6];
    const float* b1  = (const float*)d_in[7];
    const float* Wl1 = (const float*)d_in[8];
    const float* bl1 = (const float*)d_in[9];
    const float* Wl2 = (const float*)d_in[10];
    const float* bl2 = (const float*)d_in[11];

    const int N = NN, E = EE;
    const int* esrc_in = eidx;
    const int* edst_in = eidx + E;

    // d_out layout: out [N,16] | x_rel [N,512] | out_proto [512,16]
    float* out_final = (float*)d_out;
    float* x_rel     = (float*)d_out + (size_t)N * NCLS;
    float* out_proto = x_rel + (size_t)N * NPROT;

    char* w = (char*)d_ws;
    auto alloc = [&](size_t bytes) { char* p = w; w += (bytes + 255) & ~(size_t)255; return p; };
    int*   cnt      = (int*)alloc((size_t)N * 4);
    int*   cursor   = (int*)alloc((size_t)N * 4);
    float* dis      = (float*)alloc((size_t)N * 4);
    int*   excl     = (int*)alloc((size_t)N * 4);
    int*   csr_off  = (int*)alloc((size_t)(N + 1) * 4);
    int*   bsum     = (int*)alloc(1024);
    int*   boff     = (int*)alloc(1024);
    int2*  csr_e    = (int2*)alloc((size_t)E * 8);
    float* nx       = (float*)alloc((size_t)N * 4);
    float* na       = (float*)alloc((size_t)NPROT * 4);
    float* opart    = (float*)alloc((size_t)4 * NP * NCLS * 4);             // 12.8 MB
    unsigned short* xb    = (unsigned short*)alloc((size_t)NP * DIN * 2);   // 12.8 MB
    unsigned short* Wt0   = (unsigned short*)alloc((size_t)HID * DIN * 2);
    unsigned short* Wt1   = (unsigned short*)alloc((size_t)HID * HID * 2);
    unsigned short* bufAb = (unsigned short*)alloc((size_t)NP * HID * 2);   // 25.6 MB
    unsigned short* h0b   = (unsigned short*)alloc((size_t)NP * HID * 2);   // 25.6 MB
    unsigned short* aRb   = (unsigned short*)alloc((size_t)NPROT * HID * 2);
    unsigned short* a1 = bufAb;  // agg(x) [NP,128] bf16 — dead before G2 overwrites bufAb
    unsigned short* hb = h0b;    // normalized h — h0b dead once G2 has consumed it

    hipMemsetAsync(cnt, 0, (size_t)N * 4, stream);
    hipMemsetAsync(cursor, 0, (size_t)N * 4, stream);

    // CSR build
    k_count<<<(E + 255) / 256, 256, 0, stream>>>(edst_in, cnt, E);
    int NB = (N + 255) / 256;
    k_scan1<<<NB, 256, 0, stream>>>(cnt, excl, bsum, dis, N);
    k_scan2<<<1, 256, 0, stream>>>(bsum, boff, NB);
    k_scan3<<<NB, 256, 0, stream>>>(excl, boff, csr_off, N, E);
    k_fill<<<(E + 255) / 256, 256, 0, stream>>>(esrc_in, edst_in, csr_off, cursor, dis, csr_e, E);

    // prep: cast x, transpose weights (one fused launch)
    k_prep<<<CAST_BLKS + WT0_BLKS + WT1_BLKS, 256, 0, stream>>>(x, xb, W0, Wt0, W1, Wt1);

    const int MT = NP / 128;  // 391

    // layer 1 (flipped): a1 = agg(x);  h0 = relu(a1@W0 + b0)
    k_agg128<<<(N + 3) / 4, 256, 0, stream>>>(xb, csr_off, csr_e, dis, a1, N);
    k_gemm_mfma<<<dim3(HID / 128, MT), 256, 0, stream>>>(a1, Wt0, h0b, N, HID, DIN, 2, b0);

    // layer 2: h = normalize(agg(h0@W1) + b1)   (norm fused into agg epilogue)
    k_gemm_mfma<<<dim3(HID / 128, MT), 256, 0, stream>>>(h0b, Wt1, bufAb, N, HID, HID, 0, nullptr);
    k_agg256<<<(N + 3) / 4, 256, 0, stream>>>(bufAb, csr_off, csr_e, dis, b1, hb, nx, N);

    // anchors + prototype head (fused)
    k_gproto<<<NPROT, 256, 0, stream>>>(hb, prot, nx, aRb, na, Wl1, bl1, Wl2, bl2, out_proto);

    // fused: x_rel = (h @ anchors^T)/max(nx*na,eps)  AND  partial out = x_rel @ out_proto
    k_xrel_out<<<NWGX, 256, 0, stream>>>(hb, aRb, nx, na, out_proto, x_rel, opart);

    // out = log_softmax(sum of partials)
    k_reduce<<<NP * NCLS / 256, 256, 0, stream>>>(opart, out_final);
}

// Round 5
// 441.528 us; speedup vs baseline: 1.0250x; 1.0250x over previous
//
#include <hip/hip_runtime.h>
#include <hip/hip_bf16.h>
#include <math.h>

#define NN 50000
#define NP 50048          // padded to 128-multiple for MFMA tiles
#define EE 800000
#define EPAD 1150016      // padded CSR capacity: E + 7*N, rounded up
#define DIN 128
#define HID 256
#define NCLS 16
#define NPROT 512

typedef __attribute__((ext_vector_type(8))) short short8;
typedef __attribute__((ext_vector_type(4))) float f32x4;

__device__ inline unsigned short f2b(float f) {
    union { float f; unsigned u; } c; c.f = f;
    unsigned u = c.u;
    unsigned r = (u + 0x7FFFu + ((u >> 16) & 1u)) >> 16;
    return (unsigned short)r;
}
__device__ inline float b2f(unsigned short u) {
    union { unsigned u; float f; } c; c.u = ((unsigned)u) << 16; return c.f;
}

// async global->LDS, 16B per lane; LDS dest must be wave-uniform base + lane*16
#define GL2LDS16(g, l)                                                              \
    __builtin_amdgcn_global_load_lds(                                               \
        (const __attribute__((address_space(1))) unsigned int*)(g),                 \
        (__attribute__((address_space(3))) unsigned int*)(l), 16, 0, 0)

// ---------------- degree / CSR construction (node segments padded to x8) ----------------

__global__ __launch_bounds__(256) void k_count(const int* __restrict__ dst, int* __restrict__ cnt, int e) {
    int i = blockIdx.x * 256 + threadIdx.x;
    if (i < e) atomicAdd(&cnt[dst[i]], 1);
}

// block-local inclusive scan over PADDED counts; also emits dis = rsqrt(deg+1)
__global__ __launch_bounds__(256) void k_scan1(const int* __restrict__ cnt, int* __restrict__ excl,
                                               int* __restrict__ bsum, float* __restrict__ dis, int n) {
    __shared__ int s[256];
    int t = threadIdx.x;
    int i = blockIdx.x * 256 + t;
    int v = (i < n) ? cnt[i] : 0;
    if (i < n) dis[i] = rsqrtf((float)v + 1.0f);
    int vp = (v + 7) & ~7;          // pad each node's segment to a multiple of 8
    s[t] = vp; __syncthreads();
    for (int d = 1; d < 256; d <<= 1) {
        int add = (t >= d) ? s[t - d] : 0;
        __syncthreads();
        s[t] += add;
        __syncthreads();
    }
    if (i < n) excl[i] = s[t] - vp;
    if (t == 255) bsum[blockIdx.x] = s[255];
}

__global__ __launch_bounds__(256) void k_scan2(const int* __restrict__ bsum, int* __restrict__ boff, int nb) {
    __shared__ int s[256];
    int t = threadIdx.x;
    int v = (t < nb) ? bsum[t] : 0;
    s[t] = v; __syncthreads();
    for (int d = 1; d < 256; d <<= 1) {
        int add = (t >= d) ? s[t - d] : 0;
        __syncthreads();
        s[t] += add;
        __syncthreads();
    }
    if (t < nb) boff[t] = s[t] - v;
}

__global__ __launch_bounds__(256) void k_scan3(const int* __restrict__ excl, const int* __restrict__ boff,
                                               const int* __restrict__ bsum,
                                               int* __restrict__ off, int n, int nb) {
    int i = blockIdx.x * 256 + threadIdx.x;
    if (i < n) off[i] = excl[i] + boff[blockIdx.x];
    if (i == 0) off[n] = boff[nb - 1] + bsum[nb - 1];   // total padded count
}

__global__ __launch_bounds__(256) void k_fill(const int* __restrict__ src, const int* __restrict__ dst,
                                              const int* __restrict__ off, int* __restrict__ cursor,
                                              const float* __restrict__ dis,
                                              int2* __restrict__ csr_e, int e) {
    int i = blockIdx.x * 256 + threadIdx.x;
    if (i >= e) return;
    int s = src[i], d = dst[i];
    int pos = atomicAdd(&cursor[d], 1);
    csr_e[off[d] + pos] = make_int2(s, __float_as_int(dis[s] * dis[d]));
}

// ---------------- fused prep: cast x -> bf16, transpose W0/W1 -> bf16 [n][k] ----------------

#define CAST_BLKS (NN * DIN / 4 / 256)   // 6250
#define WT0_BLKS  (DIN * HID / 256)      // 128
#define WT1_BLKS  (HID * HID / 256)      // 256

__global__ __launch_bounds__(256) void k_prep(const float* __restrict__ x, unsigned short* __restrict__ xb,
                                              const float* __restrict__ W0, unsigned short* __restrict__ Wt0,
                                              const float* __restrict__ W1, unsigned short* __restrict__ Wt1) {
    int b = blockIdx.x, t = threadIdx.x;
    if (b < CAST_BLKS) {
        int i = b * 256 + t;
        float4 v = ((const float4*)x)[i];
        ushort4 o; o.x = f2b(v.x); o.y = f2b(v.y); o.z = f2b(v.z); o.w = f2b(v.w);
        ((ushort4*)xb)[i] = o;
    } else if (b < CAST_BLKS + WT0_BLKS) {
        int i = (b - CAST_BLKS) * 256 + t;
        int k = i / HID, n = i - k * HID;
        Wt0[n * DIN + k] = f2b(W0[(size_t)k * HID + n]);
    } else {
        int i = (b - CAST_BLKS - WT0_BLKS) * 256 + t;
        int k = i / HID, n = i - k * HID;
        Wt1[n * HID + k] = f2b(W1[(size_t)k * HID + n]);
    }
}

// ---------------- bf16 MFMA GEMM: C[M,Nc] = A[Mp,K] @ Bt[Nc,K]^T ----------------
// mode 0: plain bf16 store (unguarded).  mode 2: +bias[col], relu, bf16 store (unguarded).

__global__ __launch_bounds__(256) void k_gemm_mfma(const unsigned short* __restrict__ A,
                                                   const unsigned short* __restrict__ Bt,
                                                   void* __restrict__ C, int M, int Nc, int K, int mode,
                                                   const float* __restrict__ bias) {
    __shared__ __align__(16) unsigned short As[128 * 32];  // 8 KB, unpadded (global_load_lds layout)
    __shared__ __align__(16) unsigned short Bs[128 * 32];
    const int t = threadIdx.x;
    const int lane = t & 63;
    const int quad = lane >> 4;
    const int l16 = lane & 15;
    const int wv = t >> 6;
    const int wm = (wv & 1) * 64, wn = (wv >> 1) * 64;
    const int m0 = blockIdx.y * 128, n0 = blockIdx.x * 128;

    f32x4 acc[4][4];
#pragma unroll
    for (int i = 0; i < 4; ++i)
#pragma unroll
        for (int j = 0; j < 4; ++j)
#pragma unroll
            for (int r = 0; r < 4; ++r) acc[i][j][r] = 0.0f;

    const int sr = t >> 2;         // staging row 0..63 (per half)
    const int sc = (t & 3) * 8;    // short offset in row: 0,8,16,24

    for (int k0 = 0; k0 < K; k0 += 32) {
        GL2LDS16(A + (size_t)(m0 + sr) * K + k0 + sc,       &As[t * 8]);
        GL2LDS16(A + (size_t)(m0 + 64 + sr) * K + k0 + sc,  &As[2048 + t * 8]);
        GL2LDS16(Bt + (size_t)(n0 + sr) * K + k0 + sc,      &Bs[t * 8]);
        GL2LDS16(Bt + (size_t)(n0 + 64 + sr) * K + k0 + sc, &Bs[2048 + t * 8]);
        __syncthreads();
        short8 af[4], bf[4];
#pragma unroll
        for (int i = 0; i < 4; ++i)
            af[i] = *(const short8*)&As[(wm + i * 16 + l16) * 32 + quad * 8];
#pragma unroll
        for (int j = 0; j < 4; ++j)
            bf[j] = *(const short8*)&Bs[(wn + j * 16 + l16) * 32 + quad * 8];
#pragma unroll
        for (int i = 0; i < 4; ++i)
#pragma unroll
            for (int j = 0; j < 4; ++j)
                acc[i][j] = __builtin_amdgcn_mfma_f32_16x16x32_bf16(af[i], bf[j], acc[i][j], 0, 0, 0);
        __syncthreads();
    }

#pragma unroll
    for (int i = 0; i < 4; ++i) {
        int rb = m0 + wm + i * 16 + quad * 4;
#pragma unroll
        for (int j = 0; j < 4; ++j) {
            int col = n0 + wn + j * 16 + l16;
#pragma unroll
            for (int rg = 0; rg < 4; ++rg) {
                int r = rb + rg;
                float v = acc[i][j][rg];
                if (mode == 0) {
                    ((unsigned short*)C)[(size_t)r * Nc + col] = f2b(v);
                } else {
                    v = fmaxf(v + bias[col], 0.0f);
                    ((unsigned short*)C)[(size_t)r * Nc + col] = f2b(v);
                }
            }
        }
    }
}

// ---------------- GCN aggregation (128-dim, raw): one wave per node ----------------
// Padded CSR: every node segment is a multiple of 8 edges, 64B-aligned; pads are {src=0,w=0}.
// 8 unconditional gathers + 4 int4 descriptor loads per batch; launch_bounds(256,4) gives the
// register headroom to keep them all in flight (r4 lesson: masking + tight VGPR = serialization).

__global__ __launch_bounds__(256, 4) void k_agg128(const unsigned short* __restrict__ xw, const int* __restrict__ off,
                                                   const int2* __restrict__ csr, const float* __restrict__ dis,
                                                   unsigned short* __restrict__ out, int n) {
    int node = (blockIdx.x * 256 + threadIdx.x) >> 6;
    int lane = threadIdx.x & 63;
    if (node >= n) return;
    float d = dis[node];
    float w0 = d * d;
    ushort2 u = ((const ushort2*)(xw + (size_t)node * DIN))[lane];
    float a0 = w0 * b2f(u.x), a1 = w0 * b2f(u.y);
    int p = off[node], p1 = off[node + 1];
    for (; p < p1; p += 8) {
        int4 dA = *(const int4*)(csr + p);
        int4 dB = *(const int4*)(csr + p + 2);
        int4 dC = *(const int4*)(csr + p + 4);
        int4 dD = *(const int4*)(csr + p + 6);
        ushort2 v0 = ((const ushort2*)(xw + (size_t)dA.x * DIN))[lane];
        ushort2 v1 = ((const ushort2*)(xw + (size_t)dA.z * DIN))[lane];
        ushort2 v2 = ((const ushort2*)(xw + (size_t)dB.x * DIN))[lane];
        ushort2 v3 = ((const ushort2*)(xw + (size_t)dB.z * DIN))[lane];
        ushort2 v4 = ((const ushort2*)(xw + (size_t)dC.x * DIN))[lane];
        ushort2 v5 = ((const ushort2*)(xw + (size_t)dC.z * DIN))[lane];
        ushort2 v6 = ((const ushort2*)(xw + (size_t)dD.x * DIN))[lane];
        ushort2 v7 = ((const ushort2*)(xw + (size_t)dD.z * DIN))[lane];
        float w;
        w = __int_as_float(dA.y); a0 = fmaf(w, b2f(v0.x), a0); a1 = fmaf(w, b2f(v0.y), a1);
        w = __int_as_float(dA.w); a0 = fmaf(w, b2f(v1.x), a0); a1 = fmaf(w, b2f(v1.y), a1);
        w = __int_as_float(dB.y); a0 = fmaf(w, b2f(v2.x), a0); a1 = fmaf(w, b2f(v2.y), a1);
        w = __int_as_float(dB.w); a0 = fmaf(w, b2f(v3.x), a0); a1 = fmaf(w, b2f(v3.y), a1);
        w = __int_as_float(dC.y); a0 = fmaf(w, b2f(v4.x), a0); a1 = fmaf(w, b2f(v4.y), a1);
        w = __int_as_float(dC.w); a0 = fmaf(w, b2f(v5.x), a0); a1 = fmaf(w, b2f(v5.y), a1);
        w = __int_as_float(dD.y); a0 = fmaf(w, b2f(v6.x), a0); a1 = fmaf(w, b2f(v6.y), a1);
        w = __int_as_float(dD.w); a0 = fmaf(w, b2f(v7.x), a0); a1 = fmaf(w, b2f(v7.y), a1);
    }
    ushort2 o; o.x = f2b(a0); o.y = f2b(a1);
    ((ushort2*)(out + (size_t)node * DIN))[lane] = o;
}

// ---------------- GCN aggregation (256-dim): +bias then L2-normalize, emit bf16 + nx ----------------
// Same padded 8-wide unconditional gather structure.

__global__ __launch_bounds__(256, 4) void k_agg256(const unsigned short* __restrict__ xw, const int* __restrict__ off,
                                                   const int2* __restrict__ csr, const float* __restrict__ dis,
                                                   const float* __restrict__ bias,
                                                   unsigned short* __restrict__ out, float* __restrict__ nx, int n) {
    int node = (blockIdx.x * 256 + threadIdx.x) >> 6;
    int lane = threadIdx.x & 63;
    if (node >= n) return;
    float d = dis[node];
    float w0 = d * d;
    ushort4 u = ((const ushort4*)(xw + (size_t)node * HID))[lane];
    float a0 = w0 * b2f(u.x), a1 = w0 * b2f(u.y), a2 = w0 * b2f(u.z), a3 = w0 * b2f(u.w);
    int p = off[node], p1 = off[node + 1];
    for (; p < p1; p += 8) {
        int4 dA = *(const int4*)(csr + p);
        int4 dB = *(const int4*)(csr + p + 2);
        int4 dC = *(const int4*)(csr + p + 4);
        int4 dD = *(const int4*)(csr + p + 6);
        ushort4 v0 = ((const ushort4*)(xw + (size_t)dA.x * HID))[lane];
        ushort4 v1 = ((const ushort4*)(xw + (size_t)dA.z * HID))[lane];
        ushort4 v2 = ((const ushort4*)(xw + (size_t)dB.x * HID))[lane];
        ushort4 v3 = ((const ushort4*)(xw + (size_t)dB.z * HID))[lane];
        ushort4 v4 = ((const ushort4*)(xw + (size_t)dC.x * HID))[lane];
        ushort4 v5 = ((const ushort4*)(xw + (size_t)dC.z * HID))[lane];
        ushort4 v6 = ((const ushort4*)(xw + (size_t)dD.x * HID))[lane];
        ushort4 v7 = ((const ushort4*)(xw + (size_t)dD.z * HID))[lane];
        float w;
        w = __int_as_float(dA.y);
        a0 = fmaf(w, b2f(v0.x), a0); a1 = fmaf(w, b2f(v0.y), a1); a2 = fmaf(w, b2f(v0.z), a2); a3 = fmaf(w, b2f(v0.w), a3);
        w = __int_as_float(dA.w);
        a0 = fmaf(w, b2f(v1.x), a0); a1 = fmaf(w, b2f(v1.y), a1); a2 = fmaf(w, b2f(v1.z), a2); a3 = fmaf(w, b2f(v1.w), a3);
        w = __int_as_float(dB.y);
        a0 = fmaf(w, b2f(v2.x), a0); a1 = fmaf(w, b2f(v2.y), a1); a2 = fmaf(w, b2f(v2.z), a2); a3 = fmaf(w, b2f(v2.w), a3);
        w = __int_as_float(dB.w);
        a0 = fmaf(w, b2f(v3.x), a0); a1 = fmaf(w, b2f(v3.y), a1); a2 = fmaf(w, b2f(v3.z), a2); a3 = fmaf(w, b2f(v3.w), a3);
        w = __int_as_float(dC.y);
        a0 = fmaf(w, b2f(v4.x), a0); a1 = fmaf(w, b2f(v4.y), a1); a2 = fmaf(w, b2f(v4.z), a2); a3 = fmaf(w, b2f(v4.w), a3);
        w = __int_as_float(dC.w);
        a0 = fmaf(w, b2f(v5.x), a0); a1 = fmaf(w, b2f(v5.y), a1); a2 = fmaf(w, b2f(v5.z), a2); a3 = fmaf(w, b2f(v5.w), a3);
        w = __int_as_float(dD.y);
        a0 = fmaf(w, b2f(v6.x), a0); a1 = fmaf(w, b2f(v6.y), a1); a2 = fmaf(w, b2f(v6.z), a2); a3 = fmaf(w, b2f(v6.w), a3);
        w = __int_as_float(dD.w);
        a0 = fmaf(w, b2f(v7.x), a0); a1 = fmaf(w, b2f(v7.y), a1); a2 = fmaf(w, b2f(v7.z), a2); a3 = fmaf(w, b2f(v7.w), a3);
    }
    float4 b = ((const float4*)bias)[lane];
    a0 += b.x; a1 += b.y; a2 += b.z; a3 += b.w;
    // fused L2 row-normalize (reference: h /= ||h||, nx = ||h_normed|| recomputed)
    float ss = a0 * a0 + a1 * a1 + a2 * a2 + a3 * a3;
    for (int m = 32; m >= 1; m >>= 1) ss += __shfl_xor(ss, m, 64);
    float qn = sqrtf(ss);
    a0 /= qn; a1 /= qn; a2 /= qn; a3 /= qn;
    float s2 = a0 * a0 + a1 * a1 + a2 * a2 + a3 * a3;
    for (int m = 32; m >= 1; m >>= 1) s2 += __shfl_xor(s2, m, 64);
    if (lane == 0) nx[node] = sqrtf(s2);
    ushort4 o; o.x = f2b(a0); o.y = f2b(a1); o.z = f2b(a2); o.w = f2b(a3);
    ((ushort4*)(out + (size_t)node * HID))[lane] = o;
}

// ---------------- fused anchor gather + prototype head ----------------
// block = one anchor: stage h[prot[b]] row, emit aRb (bf16 for xrel GEMM) + na, then MLP + log_softmax.

__global__ __launch_bounds__(256) void k_gproto(const unsigned short* __restrict__ hb,
                                                const int* __restrict__ prot, const float* __restrict__ nx,
                                                unsigned short* __restrict__ aRb, float* __restrict__ na,
                                                const float* __restrict__ Wl1, const float* __restrict__ bl1,
                                                const float* __restrict__ Wl2, const float* __restrict__ bl2,
                                                float* __restrict__ outp) {
    __shared__ float sa[HID];
    __shared__ float st[HID];
    int row = blockIdx.x, t = threadIdx.x;
    int p = prot[row];
    unsigned short us = hb[(size_t)p * HID + t];
    aRb[(size_t)row * HID + t] = us;
    sa[t] = b2f(us);
    if (t == 0) na[row] = nx[p];
    __syncthreads();
    float acc = bl1[t];
#pragma unroll 8
    for (int k = 0; k < HID; ++k) acc = fmaf(sa[k], Wl1[k * HID + t], acc);
    st[t] = fmaxf(acc, 0.0f);
    __syncthreads();
    if (t < 64) {
        int c = t & 15, ch = t >> 4;
        float z = 0.f;
#pragma unroll 8
        for (int k = ch * 64; k < ch * 64 + 64; ++k) z = fmaf(st[k], Wl2[k * NCLS + c], z);
        z += __shfl_xor(z, 16, 64);
        z += __shfl_xor(z, 32, 64);
        z += bl2[c];
        float m = z;
        for (int d = 8; d >= 1; d >>= 1) m = fmaxf(m, __shfl_xor(m, d, 64));
        float e = expf(z - m);
        float s = e;
        for (int d = 8; d >= 1; d >>= 1) s += __shfl_xor(s, d, 64);
        if (t < 16) outp[row * NCLS + c] = z - m - logf(s);
    }
}

// ---------------- fused x_rel + partial final head ----------------
// Grid: 1564 blocks (4 n-chunks x 391 m-tiles), XCD-swizzled so the 4 chunks of one
// m-tile land on the SAME XCD (A-panel L2 reuse). Per block: 128 rows x 128 cols:
// K-loop MFMA -> rcp cosine-scale -> bf16 tile in XOR-swizzled LDS ->
//   (a) MFMA vs protoT slice -> fp32 partial out to opart[nc][NP][16]
//   (b) bf16->fp32 expand + dwordx4 fully-coalesced x_rel stores.
// LDS: 8 + 8 + 32 (Xs, XOR-swizzled) + 4.25 (pTc) = 52.25 KB -> 3 blocks/CU.

#define XSW(row, cs) (((cs) ^ (((row) & 7) << 3)))
#define NWGX (4 * (NP / 128))   // 1564

__global__ __launch_bounds__(256, 3) void k_xrel_out(const unsigned short* __restrict__ A,
                                                     const unsigned short* __restrict__ Bt,
                                                     const float* __restrict__ nx, const float* __restrict__ na,
                                                     const float* __restrict__ proto,
                                                     float* __restrict__ xrel, float* __restrict__ opart) {
    __shared__ __align__(16) unsigned short As[128 * 32];   // 8 KB
    __shared__ __align__(16) unsigned short Bs[128 * 32];   // 8 KB
    __shared__ __align__(16) unsigned short Xs[128 * 128];  // 32 KB bf16 x_rel tile (XOR-swizzled cols)
    __shared__ __align__(16) unsigned short pTc[16 * 136];  // 4.25 KB protoT slice

    // bijective XCD swizzle (m204): contiguous work ranges per XCD, work = m-major, chunk-minor
    const int bid = blockIdx.x;
    const int q = NWGX / 8, r = NWGX % 8;      // 195, 4
    const int xcd = bid & 7, li = bid >> 3;
    const int wk = (xcd < r ? xcd * (q + 1) : r * (q + 1) + (xcd - r) * q) + li;
    const int m0 = (wk >> 2) * 128;
    const int nc = wk & 3;
    const int n0 = nc * 128;

    const int t = threadIdx.x;
    const int lane = t & 63;
    const int quad = lane >> 4;
    const int l16 = lane & 15;
    const int wv = t >> 6;
    const int wm = (wv & 1) * 64, wn = (wv >> 1) * 64;

    // preload nx for this block's 16 row positions
    float nxv[4][4];
#pragma unroll
    for (int i = 0; i < 4; ++i)
#pragma unroll
        for (int rg = 0; rg < 4; ++rg) {
            int rr = m0 + wm + i * 16 + quad * 4 + rg;
            nxv[i][rg] = nx[rr < NN ? rr : NN - 1];
        }
    float nav[4];
#pragma unroll
    for (int j = 0; j < 4; ++j) nav[j] = na[n0 + wn + j * 16 + l16];

    const int sr = t >> 2;
    const int sc = (t & 3) * 8;

    f32x4 acc[4][4];
#pragma unroll
    for (int i = 0; i < 4; ++i)
#pragma unroll
        for (int j = 0; j < 4; ++j)
#pragma unroll
            for (int rr = 0; rr < 4; ++rr) acc[i][j][rr] = 0.0f;

    for (int k0 = 0; k0 < HID; k0 += 32) {
        GL2LDS16(A + (size_t)(m0 + sr) * HID + k0 + sc,       &As[t * 8]);
        GL2LDS16(A + (size_t)(m0 + 64 + sr) * HID + k0 + sc,  &As[2048 + t * 8]);
        GL2LDS16(Bt + (size_t)(n0 + sr) * HID + k0 + sc,      &Bs[t * 8]);
        GL2LDS16(Bt + (size_t)(n0 + 64 + sr) * HID + k0 + sc, &Bs[2048 + t * 8]);
        __syncthreads();
        short8 af[4], bf[4];
#pragma unroll
        for (int i = 0; i < 4; ++i)
            af[i] = *(const short8*)&As[(wm + i * 16 + l16) * 32 + quad * 8];
#pragma unroll
        for (int j = 0; j < 4; ++j)
            bf[j] = *(const short8*)&Bs[(wn + j * 16 + l16) * 32 + quad * 8];
#pragma unroll
        for (int i = 0; i < 4; ++i)
#pragma unroll
            for (int j = 0; j < 4; ++j)
                acc[i][j] = __builtin_amdgcn_mfma_f32_16x16x32_bf16(af[i], bf[j], acc[i][j], 0, 0, 0);
        __syncthreads();
    }

    // stage protoT slice for this chunk: pTc[c][kk] = bf16(proto[n0+kk][c])
    for (int i = t; i < 128 * NCLS; i += 256) {
        int kk = i >> 4, c = i & 15;
        pTc[c * 136 + kk] = f2b(proto[(n0 + kk) * NCLS + c]);
    }

    // cosine-scale (v_rcp) and stage bf16 tile into XOR-swizzled Xs
#pragma unroll
    for (int i = 0; i < 4; ++i) {
#pragma unroll
        for (int j = 0; j < 4; ++j) {
            int cl = wn + j * 16 + l16;
#pragma unroll
            for (int rg = 0; rg < 4; ++rg) {
                int row = wm + i * 16 + quad * 4 + rg;
                float s = fmaxf(nxv[i][rg] * nav[j], 1e-6f);
                float v = acc[i][j][rg] * __builtin_amdgcn_rcpf(s);
                Xs[row * 128 + XSW(row, cl)] = f2b(v);
            }
        }
    }
    __syncthreads();

    // (a) partial out: wave wv owns local rows wv*32 .. wv*32+31; k = this chunk's 128 cols
    f32x4 oacc[2];
#pragma unroll
    for (int rr = 0; rr < 4; ++rr) { oacc[0][rr] = 0.0f; oacc[1][rr] = 0.0f; }
#pragma unroll
    for (int ii = 0; ii < 2; ++ii) {
        int rb = wv * 32 + ii * 16;
#pragma unroll
        for (int ks = 0; ks < 4; ++ks) {
            int row = rb + l16;
            short8 af = *(const short8*)&Xs[row * 128 + XSW(row, ks * 32 + quad * 8)];
            short8 pb = *(const short8*)&pTc[l16 * 136 + ks * 32 + quad * 8];
            oacc[ii] = __builtin_amdgcn_mfma_f32_16x16x32_bf16(af, pb, oacc[ii], 0, 0, 0);
        }
    }
#pragma unroll
    for (int ii = 0; ii < 2; ++ii)
#pragma unroll
        for (int rg = 0; rg < 4; ++rg) {
            int lrow = wv * 32 + ii * 16 + quad * 4 + rg;
            opart[((size_t)nc * NP + m0 + lrow) * NCLS + l16] = oacc[ii][rg];
        }

    // (b) coalesced x_rel stores: bf16 -> fp32 expand, 16 lanes cover 512 B of one row
#pragma unroll
    for (int it = 0; it < 8; ++it) {
        int idx = it * 256 + t;          // 0..2047
        int row = idx >> 4;              // 0..127
        int c8 = (idx & 15) * 8;         // 0,8,..,120
        int rr = m0 + row;
        if (rr < NN) {
            short8 u = *(const short8*)&Xs[row * 128 + XSW(row, c8)];
            float* dst = &xrel[(size_t)rr * NPROT + n0 + c8];
            float4 v0, v1;
            v0.x = b2f((unsigned short)u[0]); v0.y = b2f((unsigned short)u[1]);
            v0.z = b2f((unsigned short)u[2]); v0.w = b2f((unsigned short)u[3]);
            v1.x = b2f((unsigned short)u[4]); v1.y = b2f((unsigned short)u[5]);
            v1.z = b2f((unsigned short)u[6]); v1.w = b2f((unsigned short)u[7]);
            *(float4*)dst = v0;
            *(float4*)(dst + 4) = v1;
        }
    }
}

// ---------------- final reduce: out = log_softmax(sum of 4 chunk partials) ----------------

__global__ __launch_bounds__(256) void k_reduce(const float* __restrict__ opart, float* __restrict__ out) {
    int i = blockIdx.x * 256 + threadIdx.x;   // over NP*16
    int row = i >> 4, c = i & 15;
    float z = opart[i] + opart[(size_t)NP * NCLS + i] + opart[(size_t)2 * NP * NCLS + i] +
              opart[(size_t)3 * NP * NCLS + i];
    float mx = z;
    for (int d = 8; d >= 1; d >>= 1) mx = fmaxf(mx, __shfl_xor(mx, d, 64));
    float e = expf(z - mx);
    float s = e;
    for (int d = 8; d >= 1; d >>= 1) s += __shfl_xor(s, d, 64);
    if (row < NN) out[(size_t)row * NCLS + c] = z - mx - logf(s);
}

// ---------------- launch ----------------

extern "C" void kernel_launch(void* const* d_in, const int* in_sizes, int n_in,
                              void* d_out, int out_size, void* d_ws, size_t ws_size,
                              hipStream_t stream) {
    const float* x    = (const float*)d_in[0];
    const int*   eidx = (const int*)d_in[1];
    const int*   prot = (const int*)d_in[2];
    const float* W0  = (const float*)d_in[4];
    const float* b0  = (const float*)d_in[5];
    const float* W1  = (const float*)d_in[6];
    const float* b1  = (const float*)d_in[7];
    const float* Wl1 = (const float*)d_in[8];
    const float* bl1 = (const float*)d_in[9];
    const float* Wl2 = (const float*)d_in[10];
    const float* bl2 = (const float*)d_in[11];

    const int N = NN, E = EE;
    const int* esrc_in = eidx;
    const int* edst_in = eidx + E;

    // d_out layout: out [N,16] | x_rel [N,512] | out_proto [512,16]
    float* out_final = (float*)d_out;
    float* x_rel     = (float*)d_out + (size_t)N * NCLS;
    float* out_proto = x_rel + (size_t)N * NPROT;

    char* w = (char*)d_ws;
    auto alloc = [&](size_t bytes) { char* p = w; w += (bytes + 255) & ~(size_t)255; return p; };
    int*   cnt      = (int*)alloc((size_t)N * 4);
    int*   cursor   = (int*)alloc((size_t)N * 4);
    float* dis      = (float*)alloc((size_t)N * 4);
    int*   excl     = (int*)alloc((size_t)N * 4);
    int*   csr_off  = (int*)alloc((size_t)(N + 1) * 4);
    int*   bsum     = (int*)alloc(1024);
    int*   boff     = (int*)alloc(1024);
    int2*  csr_e    = (int2*)alloc((size_t)EPAD * 8);                       // padded CSR, 9.2 MB
    float* nx       = (float*)alloc((size_t)N * 4);
    float* na       = (float*)alloc((size_t)NPROT * 4);
    float* opart    = (float*)alloc((size_t)4 * NP * NCLS * 4);             // 12.8 MB
    unsigned short* xb    = (unsigned short*)alloc((size_t)NP * DIN * 2);   // 12.8 MB
    unsigned short* Wt0   = (unsigned short*)alloc((size_t)HID * DIN * 2);
    unsigned short* Wt1   = (unsigned short*)alloc((size_t)HID * HID * 2);
    unsigned short* bufAb = (unsigned short*)alloc((size_t)NP * HID * 2);   // 25.6 MB
    unsigned short* h0b   = (unsigned short*)alloc((size_t)NP * HID * 2);   // 25.6 MB
    unsigned short* aRb   = (unsigned short*)alloc((size_t)NPROT * HID * 2);
    unsigned short* a1 = bufAb;  // agg(x) [NP,128] bf16 — dead before G2 overwrites bufAb
    unsigned short* hb = h0b;    // normalized h — h0b dead once G2 has consumed it

    hipMemsetAsync(cnt, 0, (size_t)N * 4, stream);
    hipMemsetAsync(cursor, 0, (size_t)N * 4, stream);
    hipMemsetAsync(csr_e, 0, (size_t)EPAD * 8, stream);   // pad entries = {src=0, w=0.0}

    // CSR build (node segments padded to x8 => 64B-aligned, no tail in agg loops)
    k_count<<<(E + 255) / 256, 256, 0, stream>>>(edst_in, cnt, E);
    int NB = (N + 255) / 256;
    k_scan1<<<NB, 256, 0, stream>>>(cnt, excl, bsum, dis, N);
    k_scan2<<<1, 256, 0, stream>>>(bsum, boff, NB);
    k_scan3<<<NB, 256, 0, stream>>>(excl, boff, bsum, csr_off, N, NB);
    k_fill<<<(E + 255) / 256, 256, 0, stream>>>(esrc_in, edst_in, csr_off, cursor, dis, csr_e, E);

    // prep: cast x, transpose weights (one fused launch)
    k_prep<<<CAST_BLKS + WT0_BLKS + WT1_BLKS, 256, 0, stream>>>(x, xb, W0, Wt0, W1, Wt1);

    const int MT = NP / 128;  // 391

    // layer 1 (flipped): a1 = agg(x);  h0 = relu(a1@W0 + b0)
    k_agg128<<<(N + 3) / 4, 256, 0, stream>>>(xb, csr_off, csr_e, dis, a1, N);
    k_gemm_mfma<<<dim3(HID / 128, MT), 256, 0, stream>>>(a1, Wt0, h0b, N, HID, DIN, 2, b0);

    // layer 2: h = normalize(agg(h0@W1) + b1)   (norm fused into agg epilogue)
    k_gemm_mfma<<<dim3(HID / 128, MT), 256, 0, stream>>>(h0b, Wt1, bufAb, N, HID, HID, 0, nullptr);
    k_agg256<<<(N + 3) / 4, 256, 0, stream>>>(bufAb, csr_off, csr_e, dis, b1, hb, nx, N);

    // anchors + prototype head (fused)
    k_gproto<<<NPROT, 256, 0, stream>>>(hb, prot, nx, aRb, na, Wl1, bl1, Wl2, bl2, out_proto);

    // fused: x_rel = (h @ anchors^T)/max(nx*na,eps)  AND  partial out = x_rel @ out_proto
    k_xrel_out<<<NWGX, 256, 0, stream>>>(hb, aRb, nx, na, out_proto, x_rel, opart);

    // out = log_softmax(sum of partials)
    k_reduce<<<NP * NCLS / 256, 256, 0, stream>>>(opart, out_final);
}